// Round 5
// baseline (149.025 us; speedup 1.0000x reference)
//
#include <hip/hip_runtime.h>

#define OD 26
#define OH 122
#define OW 122
#define GS (128*128)

// Guide LDS tile for an 8x8x4 voxel block: logical 14 x 14 x 10, stored with
// row stride 36 (36 mod 32 == 4 -> the 8x8 wave footprint ty*36+tx covers
// each of the 32 banks exactly twice = conflict-free; stride 14 gave 3-way
// aliasing = 4.0M conflict cycles in R4).
#define TLX 14
#define TLY 14
#define TLZ 10
#define TSR 36                  // padded row stride
#define TSL (TLY*TSR)           // 504: padded slice stride
#define TLN_LOG (TLX*TLY*TLZ)   // 1960 logical elements to stage

// One fused kernel. Per block: stage guide tile (LDS) + redundantly compute
// the voxel-independent domain kernel dk[27] (tiny: 125x27 + 27x27 FMA),
// then R1's proven spill-free full-t0[125] per-thread compute.
//
// DO NOT add a min-waves launch-bounds arg or restructure into a rolling
// register window: R2 ((64,4)) and R3 (rolling window) both made the
// allocator target high occupancy and spill 600-800 B/thread to scratch
// (WRITE_SIZE 0.9-1.25 GB, 3x slower). Full t0[125] + plain bounds is the
// only structure the allocator has handled spill-free (R1/R4).
__global__ __launch_bounds__(256) void jbf_main_kernel(
        const float* __restrict__ x, const float* __restrict__ guide,
        const float* __restrict__ rw0p, const float* __restrict__ rb0p,
        const float* __restrict__ rw1p, const float* __restrict__ rb1p,
        const float* __restrict__ dn,
        const float* __restrict__ dw0, const float* __restrict__ db0,
        const float* __restrict__ dw1, const float* __restrict__ db1,
        float* __restrict__ out) {
    __shared__ float gl[TLZ * TSL];   // 5040 floats
    __shared__ float d0[125];
    __shared__ float dkl[27];

    const int t  = threadIdx.x;
    const int xb = blockIdx.x * 8;
    const int yb = blockIdx.y * 8;
    const int zb = blockIdx.z * 4;

    // --- Phase 1a: cooperative guide staging (coords clamped; edge tiles
    // read dup rows, in-range voxels only consume in-bounds neighbors).
    #pragma unroll
    for (int ii = 0; ii < 8; ++ii) {
        const int i = t + ii * 256;
        if (i < TLN_LOG) {
            const int gx = i % TLX;
            const int gy = (i / TLX) % TLY;
            const int gz = i / (TLX * TLY);
            const int sx = min(xb + gx, 127);
            const int sy = min(yb + gy, 127);
            const int sz = min(zb + gz, 31);
            gl[gz*TSL + gy*TSR + gx] = guide[sz*GS + sy*128 + sx];
        }
    }
    // --- Phase 1b: domain conv stage 1 (redundant per block; dn is 3KB and
    // L1/L2-hot, cost ~hundreds of cycles amortized over the whole block).
    if (t < 125) {
        const int dz = t / 25, dy = (t / 5) % 5, dx = t % 5;
        float acc = db0[0];
        #pragma unroll
        for (int kz = 0; kz < 3; ++kz)
            #pragma unroll
            for (int ky = 0; ky < 3; ++ky)
                #pragma unroll
                for (int kx = 0; kx < 3; ++kx)
                    acc = fmaf(dw0[kz*9 + ky*3 + kx],
                               dn[(1+dz+kz)*81 + (1+dy+ky)*9 + (1+dx+kx)], acc);
        d0[t] = fmaxf(acc, 0.0f);
    }
    __syncthreads();
    // --- Phase 2: domain conv stage 2 -> dk[27] in LDS.
    if (t < 27) {
        const int rz = t / 9, ry = (t / 3) % 3, rx = t % 3;
        float acc = db1[0];
        #pragma unroll
        for (int kz = 0; kz < 3; ++kz)
            #pragma unroll
            for (int ky = 0; ky < 3; ++ky)
                #pragma unroll
                for (int kx = 0; kx < 3; ++kx)
                    acc = fmaf(dw1[kz*9 + ky*3 + kx],
                               d0[(rz+kz)*25 + (ry+ky)*5 + (rx+kx)], acc);
        dkl[t] = fmaxf(acc, 0.0f);
    }
    __syncthreads();

    // --- Phase 3: per-voxel compute (R4 structure, reads from padded LDS).
    const int tx = t & 7;
    const int ty = (t >> 3) & 7;
    const int tz = t >> 6;
    const int x0 = xb + tx;
    const int y0 = yb + ty;
    const int z0 = zb + tz;
    if (x0 >= OW || y0 >= OH || z0 >= OD) return;

    // Wave-uniform weights -> scalar regs.
    float rw0[27], rw1[27];
    #pragma unroll
    for (int i = 0; i < 27; ++i) { rw0[i] = rw0p[i]; rw1[i] = rw1p[i]; }
    const float rb0 = rb0p[0], rb1 = rb1p[0];

    // Per-thread LDS base: all inner reads are base + compile-time offset.
    const float* glb = &gl[tz*TSL + ty*TSR + tx];
    const float gc = glb[3*TSL + 3*TSR + 3];

    // conv1: full 5x5x5 t0, accumulated row-by-row over the 49 guide rows.
    float t0[125];
    #pragma unroll
    for (int i = 0; i < 125; ++i) t0[i] = rb0;

    #pragma unroll
    for (int gz = 0; gz < 7; ++gz) {
        #pragma unroll
        for (int gy = 0; gy < 7; ++gy) {
            float s[7];
            #pragma unroll
            for (int j = 0; j < 7; ++j)
                s[j] = glb[gz*TSL + gy*TSR + j] - gc;   // ds_read imm offset
            #pragma unroll
            for (int kz = 0; kz < 3; ++kz) {
                const int tz1 = gz - kz;
                if (tz1 < 0 || tz1 > 4) continue;        // folds at compile time
                #pragma unroll
                for (int ky = 0; ky < 3; ++ky) {
                    const int ty1 = gy - ky;
                    if (ty1 < 0 || ty1 > 4) continue;    // folds at compile time
                    #pragma unroll
                    for (int txx = 0; txx < 5; ++txx)
                        #pragma unroll
                        for (int kx = 0; kx < 3; ++kx)
                            t0[tz1*25 + ty1*5 + txx] =
                                fmaf(rw0[kz*9 + ky*3 + kx], fabsf(s[txx + kx]),
                                     t0[tz1*25 + ty1*5 + txx]);
                }
            }
        }
    }
    #pragma unroll
    for (int i = 0; i < 125; ++i) t0[i] = fmaxf(t0[i], 0.0f);

    // conv2 fused with weighting + reduction (rk never materialized).
    float num = 0.0f, den = 0.0f;
    const float* xbp = x + (z0+2)*GS + (y0+2)*128 + (x0+2);
    #pragma unroll
    for (int rz = 0; rz < 3; ++rz)
        #pragma unroll
        for (int ry = 0; ry < 3; ++ry)
            #pragma unroll
            for (int rx = 0; rx < 3; ++rx) {
                float acc = rb1;
                #pragma unroll
                for (int kz = 0; kz < 3; ++kz)
                    #pragma unroll
                    for (int ky = 0; ky < 3; ++ky)
                        #pragma unroll
                        for (int kx = 0; kx < 3; ++kx)
                            acc = fmaf(rw1[kz*9 + ky*3 + kx],
                                       t0[(rz+kz)*25 + (ry+ky)*5 + (rx+kx)], acc);
                const float w = dkl[rz*9 + ry*3 + rx] * fmaxf(acc, 0.0f) + 1e-10f;
                den += w;
                num = fmaf(w, xbp[rz*GS + ry*128 + rx], num);
            }

    out[(z0*OH + y0)*OW + x0] = num / den;
}

extern "C" void kernel_launch(void* const* d_in, const int* in_sizes, int n_in,
                              void* d_out, int out_size, void* d_ws, size_t ws_size,
                              hipStream_t stream) {
    const float* x     = (const float*)d_in[0];
    const float* dn    = (const float*)d_in[1];
    const float* guide = (const float*)d_in[2];
    const float* rw0   = (const float*)d_in[3];
    const float* rb0   = (const float*)d_in[4];
    const float* rw1   = (const float*)d_in[5];
    const float* rb1   = (const float*)d_in[6];
    const float* dw0   = (const float*)d_in[7];
    const float* db0   = (const float*)d_in[8];
    const float* dw1   = (const float*)d_in[9];
    const float* db1   = (const float*)d_in[10];
    float* out = (float*)d_out;

    dim3 grid((OW + 7) / 8, (OH + 7) / 8, (OD + 3) / 4);   // 16 x 16 x 7
    jbf_main_kernel<<<grid, 256, 0, stream>>>(x, guide, rw0, rb0, rw1, rb1,
                                              dn, dw0, db0, dw1, db1, out);
}